// Round 1
// baseline (1013.414 us; speedup 1.0000x reference)
//
#include <hip/hip_runtime.h>
#include <cstdint>
#include <cstddef>

#define NN 8192
#define KFIN 1024
#define KFOUT 256
#define MAXD 192
#define LRALPHA 0.2f

// ---------------------------------------------------------------------------
// Kernel A: dense adj -> CSR neighbor lists (stable order via wave ballot),
// degree, and s2 = off-diagonal degree. Deterministic.
// ---------------------------------------------------------------------------
__global__ void __launch_bounds__(256) k_build_csr(
    const float* __restrict__ adj, int* __restrict__ nbr,
    int* __restrict__ deg, int* __restrict__ s2v) {
  const int wave = threadIdx.x >> 6;
  const int lane = threadIdx.x & 63;
  const int row = blockIdx.x * 4 + wave;
  const float* arow = adj + (size_t)row * NN;
  int* outp = nbr + (size_t)row * MAXD;
  int count = 0;
  int dflag = 0;
  for (int c0 = 0; c0 < NN; c0 += 64) {
    const int c = c0 + lane;
    const float v = arow[c];
    const unsigned long long m = __ballot(v > 0.0f);
    if (v > 0.0f) {
      const int pos = count + (int)__popcll(m & ((1ull << lane) - 1ull));
      if (pos < MAXD) outp[pos] = c;
      if (c == row) dflag = 1;
    }
    count += (int)__popcll(m);
  }
  const int anyd = __any(dflag) ? 1 : 0;
  if (lane == 0) {
    deg[row] = count < MAXD ? count : MAXD;
    s2v[row] = count - anyd;
  }
}

// ---------------------------------------------------------------------------
// Kernel B: Wh = h @ W, f32 tiled GEMM (64x64 tile, 4x4 per thread, BK=16).
// ---------------------------------------------------------------------------
__global__ void __launch_bounds__(256) k_gemm(
    const float* __restrict__ A, const float* __restrict__ B,
    float* __restrict__ C) {
  __shared__ float As[16][65];
  __shared__ float Bs[16][65];
  const int tid = threadIdx.x;
  const int brow = blockIdx.y * 64;
  const int bcol = blockIdx.x * 64;
  const int tx = tid & 15;
  const int ty = tid >> 4;
  float acc[4][4];
#pragma unroll
  for (int i = 0; i < 4; ++i)
#pragma unroll
    for (int j = 0; j < 4; ++j) acc[i][j] = 0.0f;
  const int ar = tid >> 2;
  const int ac = (tid & 3) << 2;
  const int br = tid >> 4;
  const int bc = (tid & 15) << 2;
  for (int k0 = 0; k0 < KFIN; k0 += 16) {
    const float4 av =
        *reinterpret_cast<const float4*>(A + (size_t)(brow + ar) * KFIN + k0 + ac);
    const float4 bv =
        *reinterpret_cast<const float4*>(B + (size_t)(k0 + br) * KFOUT + bcol + bc);
    As[ac + 0][ar] = av.x;
    As[ac + 1][ar] = av.y;
    As[ac + 2][ar] = av.z;
    As[ac + 3][ar] = av.w;
    Bs[br][bc + 0] = bv.x;
    Bs[br][bc + 1] = bv.y;
    Bs[br][bc + 2] = bv.z;
    Bs[br][bc + 3] = bv.w;
    __syncthreads();
#pragma unroll
    for (int kk = 0; kk < 16; ++kk) {
      const float a0 = As[kk][ty * 4 + 0];
      const float a1 = As[kk][ty * 4 + 1];
      const float a2 = As[kk][ty * 4 + 2];
      const float a3 = As[kk][ty * 4 + 3];
      const float b0 = Bs[kk][tx * 4 + 0];
      const float b1 = Bs[kk][tx * 4 + 1];
      const float b2 = Bs[kk][tx * 4 + 2];
      const float b3 = Bs[kk][tx * 4 + 3];
      acc[0][0] += a0 * b0; acc[0][1] += a0 * b1; acc[0][2] += a0 * b2; acc[0][3] += a0 * b3;
      acc[1][0] += a1 * b0; acc[1][1] += a1 * b1; acc[1][2] += a1 * b2; acc[1][3] += a1 * b3;
      acc[2][0] += a2 * b0; acc[2][1] += a2 * b1; acc[2][2] += a2 * b2; acc[2][3] += a2 * b3;
      acc[3][0] += a3 * b0; acc[3][1] += a3 * b1; acc[3][2] += a3 * b2; acc[3][3] += a3 * b3;
    }
    __syncthreads();
  }
#pragma unroll
  for (int i = 0; i < 4; ++i) {
#pragma unroll
    for (int j = 0; j < 4; ++j) {
      C[(size_t)(brow + ty * 4 + i) * KFOUT + bcol + tx * 4 + j] = acc[i][j];
    }
  }
}

// ---------------------------------------------------------------------------
// Kernel C: Wh1 = Wh @ a[:256], Wh2 = Wh @ a[256:], one block per row.
// ---------------------------------------------------------------------------
__global__ void __launch_bounds__(256) k_rowdots(
    const float* __restrict__ Wh, const float* __restrict__ a,
    float* __restrict__ Wh1, float* __restrict__ Wh2) {
  __shared__ float sA[256];
  __shared__ float sB[256];
  const int row = blockIdx.x;
  const int t = threadIdx.x;
  const float w = Wh[(size_t)row * KFOUT + t];
  sA[t] = w * a[t];
  sB[t] = w * a[KFOUT + t];
  __syncthreads();
  for (int s = 128; s > 0; s >>= 1) {
    if (t < s) {
      sA[t] += sA[t + s];
      sB[t] += sB[t + s];
    }
    __syncthreads();
  }
  if (t == 0) {
    Wh1[row] = sA[0];
    Wh2[row] = sB[0];
  }
}

// ---------------------------------------------------------------------------
// Kernel D1: per-row softmax stats (max m, denom Z) over neighbor list.
// e_ij = leakyrelu(Wh1[i] + Wh2[j]). One wave per row, deterministic.
// ---------------------------------------------------------------------------
__global__ void __launch_bounds__(256) k_stats(
    const int* __restrict__ nbr, const int* __restrict__ deg,
    const float* __restrict__ Wh1, const float* __restrict__ Wh2,
    float* __restrict__ mrow, float* __restrict__ Zrow) {
  const int wave = threadIdx.x >> 6;
  const int lane = threadIdx.x & 63;
  const int row = blockIdx.x * 4 + wave;
  const int d = deg[row];
  const int* cols = nbr + (size_t)row * MAXD;
  const float w1 = Wh1[row];
  float mx = -1e30f;
  for (int t = lane; t < d; t += 64) {
    float e = w1 + Wh2[cols[t]];
    e = e > 0.0f ? e : LRALPHA * e;
    mx = fmaxf(mx, e);
  }
  for (int o = 32; o > 0; o >>= 1) mx = fmaxf(mx, __shfl_xor(mx, o));
  float sum = 0.0f;
  for (int t = lane; t < d; t += 64) {
    float e = w1 + Wh2[cols[t]];
    e = e > 0.0f ? e : LRALPHA * e;
    sum += expf(e - mx);
  }
  for (int o = 32; o > 0; o >>= 1) sum += __shfl_xor(sum, o);
  if (lane == 0) {
    mrow[row] = mx;
    Zrow[row] = (d > 0) ? sum : 1.0f;
  }
}

// ---------------------------------------------------------------------------
// Kernel D2: attention CSR values (row-normalized) plus packed "transpose"
// edges: for row k, edgesT[k][t] = (j, att[j,k]) for j = nbr[k][t].
// att[j,k] = exp(lrelu(Wh1[j]+Wh2[k]) - m_j) / Z_j  (closed form).
// ---------------------------------------------------------------------------
__global__ void __launch_bounds__(256) k_att(
    const int* __restrict__ nbr, const int* __restrict__ deg,
    const float* __restrict__ Wh1, const float* __restrict__ Wh2,
    const float* __restrict__ mrow, const float* __restrict__ Zrow,
    float* __restrict__ att, int2* __restrict__ edgesT) {
  const int wave = threadIdx.x >> 6;
  const int lane = threadIdx.x & 63;
  const int row = blockIdx.x * 4 + wave;
  const int d = deg[row];
  const int* cols = nbr + (size_t)row * MAXD;
  const float w1r = Wh1[row];
  const float w2r = Wh2[row];
  const float mr = mrow[row];
  const float invZr = 1.0f / Zrow[row];
  for (int t = lane; t < d; t += 64) {
    const int j = cols[t];
    float e = w1r + Wh2[j];
    e = e > 0.0f ? e : LRALPHA * e;
    att[(size_t)row * MAXD + t] = expf(e - mr) * invZr;
    float e2 = Wh1[j] + w2r;
    e2 = e2 > 0.0f ? e2 : LRALPHA * e2;
    const float v = expf(e2 - mrow[j]) / Zrow[j];
    edgesT[(size_t)row * MAXD + t] = make_int2(j, __float_as_int(v));
  }
}

// ---------------------------------------------------------------------------
// Kernel E: per row i (one wave, dense 8192-f32 comb row in LDS):
//   comb = att_row_i + sum_k att[i,k] * att[:,k]  (SpGEMM row of A A^T)
//   zero diagonal, radix-select s2-th largest, emit binary row.
// Fully deterministic (sequential k loop, disjoint scatter within each k).
// ---------------------------------------------------------------------------
__global__ void __launch_bounds__(64) k_twostep(
    const int* __restrict__ nbr, const int* __restrict__ deg,
    const int* __restrict__ s2v, const float* __restrict__ att,
    const int2* __restrict__ edgesT, float* __restrict__ out1) {
  __shared__ float comb[NN];
  __shared__ unsigned int hist[256];
  __shared__ unsigned int shPrefix;
  __shared__ int shRemaining;
  const int lane = threadIdx.x;
  const int row = blockIdx.x;
  const float4 z4 = make_float4(0.0f, 0.0f, 0.0f, 0.0f);
  for (int j = lane * 4; j < NN; j += 256)
    *reinterpret_cast<float4*>(&comb[j]) = z4;
  __syncthreads();
  const int d = deg[row];
  const int* cols = nbr + (size_t)row * MAXD;
  const float* arow = att + (size_t)row * MAXD;
  for (int kidx = 0; kidx < d; ++kidx) {
    const int k = cols[kidx];
    const float w = arow[kidx];
    const int dk = deg[k];
    const int2* ek = edgesT + (size_t)k * MAXD;
    for (int t = lane; t < dk; t += 64) {
      const int2 e = ek[t];  // distinct e.x within a k -> no conflict
      comb[e.x] += w * __int_as_float(e.y);
    }
    __syncthreads();
  }
  for (int t = lane; t < d; t += 64) comb[cols[t]] += arow[t];
  __syncthreads();
  if (lane == 0) comb[row] = 0.0f;
  __syncthreads();
  const int kk = s2v[row];
  const size_t obase = (size_t)row * NN;
  if (kk <= 0) {
    for (int j = lane * 4; j < NN; j += 256)
      *reinterpret_cast<float4*>(&out1[obase + j]) = z4;
    return;
  }
  // radix select: kk-th largest of comb (all values >= 0 -> uint order).
  unsigned int prefix = 0u;
  int remaining = kk;
  for (int pass = 0; pass < 4; ++pass) {
    const int shift = 24 - 8 * pass;
    const unsigned int pmask = (pass == 0) ? 0u : (0xFFFFFFFFu << (shift + 8));
    for (int b = lane; b < 256; b += 64) hist[b] = 0u;
    __syncthreads();
    for (int j = lane; j < NN; j += 64) {
      const unsigned int u = __float_as_uint(comb[j]);
      if ((u & pmask) == prefix) atomicAdd(&hist[(u >> shift) & 255u], 1u);
    }
    __syncthreads();
    const int bHi = 255 - 4 * lane;  // lane 0 owns highest bins
    const unsigned int c0 = hist[bHi];
    const unsigned int c1 = hist[bHi - 1];
    const unsigned int c2 = hist[bHi - 2];
    const unsigned int c3 = hist[bHi - 3];
    const unsigned int gs = c0 + c1 + c2 + c3;
    unsigned int run = gs;
    for (int o = 1; o < 64; o <<= 1) {
      const unsigned int tt = __shfl_up(run, o);
      if (lane >= o) run += tt;
    }
    const unsigned int pre = run - gs;  // count in strictly higher bins
    const unsigned int rem = (unsigned int)remaining;
    if (pre < rem && pre + gs >= rem) {  // exactly one lane hits
      unsigned int above;
      int digit;
      if (pre + c0 >= rem) { digit = bHi; above = pre; }
      else if (pre + c0 + c1 >= rem) { digit = bHi - 1; above = pre + c0; }
      else if (pre + c0 + c1 + c2 >= rem) { digit = bHi - 2; above = pre + c0 + c1; }
      else { digit = bHi - 3; above = pre + c0 + c1 + c2; }
      shPrefix = prefix | ((unsigned int)digit << shift);
      shRemaining = remaining - (int)above;
    }
    __syncthreads();
    prefix = shPrefix;
    remaining = shRemaining;
    __syncthreads();
  }
  const float thr = __uint_as_float(prefix);  // exact kk-th largest value
  for (int j = lane * 4; j < NN; j += 256) {
    const float4 cv = *reinterpret_cast<const float4*>(&comb[j]);
    float4 ov;
    ov.x = (cv.x >= thr && cv.x > 0.0f) ? 1.0f : 0.0f;
    ov.y = (cv.y >= thr && cv.y > 0.0f) ? 1.0f : 0.0f;
    ov.z = (cv.z >= thr && cv.z > 0.0f) ? 1.0f : 0.0f;
    ov.w = (cv.w >= thr && cv.w > 0.0f) ? 1.0f : 0.0f;
    *reinterpret_cast<float4*>(&out1[obase + j]) = ov;
  }
}

// ---------------------------------------------------------------------------
// Kernel F: h_prime = attention @ Wh (sparse x dense), then ELU.
// One block per row, one thread per output column. Deterministic order.
// ---------------------------------------------------------------------------
__global__ void __launch_bounds__(256) k_hprime(
    const int* __restrict__ nbr, const int* __restrict__ deg,
    const float* __restrict__ att, const float* __restrict__ Wh,
    float* __restrict__ out0) {
  const int row = blockIdx.x;
  const int c = threadIdx.x;
  const int d = deg[row];
  const int* cols = nbr + (size_t)row * MAXD;
  const float* arow = att + (size_t)row * MAXD;
  float acc = 0.0f;
  for (int t = 0; t < d; ++t) {
    acc += arow[t] * Wh[(size_t)cols[t] * KFOUT + c];
  }
  out0[(size_t)row * KFOUT + c] = acc > 0.0f ? acc : expm1f(acc);
}

extern "C" void kernel_launch(void* const* d_in, const int* in_sizes, int n_in,
                              void* d_out, int out_size, void* d_ws, size_t ws_size,
                              hipStream_t stream) {
  const float* h = (const float*)d_in[0];
  const float* adj = (const float*)d_in[1];
  const float* W = (const float*)d_in[2];
  const float* a = (const float*)d_in[3];

  float* out0 = (float*)d_out;                  // [8192, 256] elu(h_prime)
  float* out1 = out0 + (size_t)NN * KFOUT;      // [8192, 8192] adj_resize

  // workspace layout (~33.8 MB)
  float* Wh = (float*)d_ws;                        // 8192*256
  float* Wh1 = Wh + (size_t)NN * KFOUT;            // 8192
  float* Wh2 = Wh1 + NN;                           // 8192
  float* mrow = Wh2 + NN;                          // 8192
  float* Zrow = mrow + NN;                         // 8192
  float* att = Zrow + NN;                          // 8192*MAXD
  float* edgesF = att + (size_t)NN * MAXD;         // 8192*MAXD int2
  int2* edgesT = (int2*)edgesF;
  int* nbr = (int*)(edgesF + (size_t)NN * MAXD * 2);  // 8192*MAXD
  int* deg = nbr + (size_t)NN * MAXD;              // 8192
  int* s2v = deg + NN;                             // 8192

  k_build_csr<<<NN / 4, 256, 0, stream>>>(adj, nbr, deg, s2v);
  dim3 ggrid(KFOUT / 64, NN / 64);
  k_gemm<<<ggrid, 256, 0, stream>>>(h, W, Wh);
  k_rowdots<<<NN, 256, 0, stream>>>(Wh, a, Wh1, Wh2);
  k_stats<<<NN / 4, 256, 0, stream>>>(nbr, deg, Wh1, Wh2, mrow, Zrow);
  k_att<<<NN / 4, 256, 0, stream>>>(nbr, deg, Wh1, Wh2, mrow, Zrow, att, edgesT);
  k_twostep<<<NN, 64, 0, stream>>>(nbr, deg, s2v, att, edgesT, out1);
  k_hprime<<<NN, 256, 0, stream>>>(nbr, deg, att, Wh, out0);
}

// Round 2
// 796.244 us; speedup vs baseline: 1.2727x; 1.2727x over previous
//
#include <hip/hip_runtime.h>
#include <cstdint>
#include <cstddef>

#define NN 8192
#define KFIN 1024
#define KFOUT 256
#define MAXD 192
#define LRALPHA 0.2f

// ---------------------------------------------------------------------------
// Kernel A: dense adj -> CSR neighbor lists (stable order via 4x ballot on
// float4 loads), degree, and s2 = off-diagonal degree. Deterministic.
// ---------------------------------------------------------------------------
__global__ void __launch_bounds__(256) k_build_csr(
    const float* __restrict__ adj, int* __restrict__ nbr,
    int* __restrict__ deg, int* __restrict__ s2v) {
  const int wave = threadIdx.x >> 6;
  const int lane = threadIdx.x & 63;
  const int row = blockIdx.x * 4 + wave;
  const float* arow = adj + (size_t)row * NN;
  int* outp = nbr + (size_t)row * MAXD;
  int count = 0;
  int dflag = 0;
  const unsigned long long below = (1ull << lane) - 1ull;
  for (int c0 = 0; c0 < NN; c0 += 256) {
    const int c = c0 + lane * 4;
    const float4 v = *reinterpret_cast<const float4*>(arow + c);
    const unsigned long long m0 = __ballot(v.x > 0.0f);
    const unsigned long long m1 = __ballot(v.y > 0.0f);
    const unsigned long long m2 = __ballot(v.z > 0.0f);
    const unsigned long long m3 = __ballot(v.w > 0.0f);
    int pos = count + (int)(__popcll(m0 & below) + __popcll(m1 & below) +
                            __popcll(m2 & below) + __popcll(m3 & below));
    if (v.x > 0.0f) { if (pos < MAXD) outp[pos] = c + 0; ++pos; if (c + 0 == row) dflag = 1; }
    if (v.y > 0.0f) { if (pos < MAXD) outp[pos] = c + 1; ++pos; if (c + 1 == row) dflag = 1; }
    if (v.z > 0.0f) { if (pos < MAXD) outp[pos] = c + 2; ++pos; if (c + 2 == row) dflag = 1; }
    if (v.w > 0.0f) { if (pos < MAXD) outp[pos] = c + 3; ++pos; if (c + 3 == row) dflag = 1; }
    count += (int)(__popcll(m0) + __popcll(m1) + __popcll(m2) + __popcll(m3));
  }
  const int anyd = __any(dflag) ? 1 : 0;
  if (lane == 0) {
    deg[row] = count < MAXD ? count : MAXD;
    s2v[row] = count - anyd;
  }
}

// ---------------------------------------------------------------------------
// Kernel B: Wh = h @ W, f32 tiled GEMM (64x64 tile, 4x4 per thread, BK=16).
// ---------------------------------------------------------------------------
__global__ void __launch_bounds__(256) k_gemm(
    const float* __restrict__ A, const float* __restrict__ B,
    float* __restrict__ C) {
  __shared__ float As[16][65];
  __shared__ float Bs[16][65];
  const int tid = threadIdx.x;
  const int brow = blockIdx.y * 64;
  const int bcol = blockIdx.x * 64;
  const int tx = tid & 15;
  const int ty = tid >> 4;
  float acc[4][4];
#pragma unroll
  for (int i = 0; i < 4; ++i)
#pragma unroll
    for (int j = 0; j < 4; ++j) acc[i][j] = 0.0f;
  const int ar = tid >> 2;
  const int ac = (tid & 3) << 2;
  const int br = tid >> 4;
  const int bc = (tid & 15) << 2;
  for (int k0 = 0; k0 < KFIN; k0 += 16) {
    const float4 av =
        *reinterpret_cast<const float4*>(A + (size_t)(brow + ar) * KFIN + k0 + ac);
    const float4 bv =
        *reinterpret_cast<const float4*>(B + (size_t)(k0 + br) * KFOUT + bcol + bc);
    As[ac + 0][ar] = av.x;
    As[ac + 1][ar] = av.y;
    As[ac + 2][ar] = av.z;
    As[ac + 3][ar] = av.w;
    Bs[br][bc + 0] = bv.x;
    Bs[br][bc + 1] = bv.y;
    Bs[br][bc + 2] = bv.z;
    Bs[br][bc + 3] = bv.w;
    __syncthreads();
#pragma unroll
    for (int kk = 0; kk < 16; ++kk) {
      const float a0 = As[kk][ty * 4 + 0];
      const float a1 = As[kk][ty * 4 + 1];
      const float a2 = As[kk][ty * 4 + 2];
      const float a3 = As[kk][ty * 4 + 3];
      const float b0 = Bs[kk][tx * 4 + 0];
      const float b1 = Bs[kk][tx * 4 + 1];
      const float b2 = Bs[kk][tx * 4 + 2];
      const float b3 = Bs[kk][tx * 4 + 3];
      acc[0][0] += a0 * b0; acc[0][1] += a0 * b1; acc[0][2] += a0 * b2; acc[0][3] += a0 * b3;
      acc[1][0] += a1 * b0; acc[1][1] += a1 * b1; acc[1][2] += a1 * b2; acc[1][3] += a1 * b3;
      acc[2][0] += a2 * b0; acc[2][1] += a2 * b1; acc[2][2] += a2 * b2; acc[2][3] += a2 * b3;
      acc[3][0] += a3 * b0; acc[3][1] += a3 * b1; acc[3][2] += a3 * b2; acc[3][3] += a3 * b3;
    }
    __syncthreads();
  }
#pragma unroll
  for (int i = 0; i < 4; ++i) {
#pragma unroll
    for (int j = 0; j < 4; ++j) {
      C[(size_t)(brow + ty * 4 + i) * KFOUT + bcol + tx * 4 + j] = acc[i][j];
    }
  }
}

// ---------------------------------------------------------------------------
// Kernel C: Wh1 = Wh @ a[:256], Wh2 = Wh @ a[256:], one block per row.
// ---------------------------------------------------------------------------
__global__ void __launch_bounds__(256) k_rowdots(
    const float* __restrict__ Wh, const float* __restrict__ a,
    float* __restrict__ Wh1, float* __restrict__ Wh2) {
  __shared__ float sA[256];
  __shared__ float sB[256];
  const int row = blockIdx.x;
  const int t = threadIdx.x;
  const float w = Wh[(size_t)row * KFOUT + t];
  sA[t] = w * a[t];
  sB[t] = w * a[KFOUT + t];
  __syncthreads();
  for (int s = 128; s > 0; s >>= 1) {
    if (t < s) {
      sA[t] += sA[t + s];
      sB[t] += sB[t + s];
    }
    __syncthreads();
  }
  if (t == 0) {
    Wh1[row] = sA[0];
    Wh2[row] = sB[0];
  }
}

// ---------------------------------------------------------------------------
// Kernel D1: per-row softmax stats (max m, denom Z) over neighbor list.
// ---------------------------------------------------------------------------
__global__ void __launch_bounds__(256) k_stats(
    const int* __restrict__ nbr, const int* __restrict__ deg,
    const float* __restrict__ Wh1, const float* __restrict__ Wh2,
    float* __restrict__ mrow, float* __restrict__ Zrow) {
  const int wave = threadIdx.x >> 6;
  const int lane = threadIdx.x & 63;
  const int row = blockIdx.x * 4 + wave;
  const int d = deg[row];
  const int* cols = nbr + (size_t)row * MAXD;
  const float w1 = Wh1[row];
  float mx = -1e30f;
  for (int t = lane; t < d; t += 64) {
    float e = w1 + Wh2[cols[t]];
    e = e > 0.0f ? e : LRALPHA * e;
    mx = fmaxf(mx, e);
  }
  for (int o = 32; o > 0; o >>= 1) mx = fmaxf(mx, __shfl_xor(mx, o));
  float sum = 0.0f;
  for (int t = lane; t < d; t += 64) {
    float e = w1 + Wh2[cols[t]];
    e = e > 0.0f ? e : LRALPHA * e;
    sum += expf(e - mx);
  }
  for (int o = 32; o > 0; o >>= 1) sum += __shfl_xor(sum, o);
  if (lane == 0) {
    mrow[row] = mx;
    Zrow[row] = (d > 0) ? sum : 1.0f;
  }
}

// ---------------------------------------------------------------------------
// Kernel D2: attention CSR values + packed transpose-edge values.
// ---------------------------------------------------------------------------
__global__ void __launch_bounds__(256) k_att(
    const int* __restrict__ nbr, const int* __restrict__ deg,
    const float* __restrict__ Wh1, const float* __restrict__ Wh2,
    const float* __restrict__ mrow, const float* __restrict__ Zrow,
    float* __restrict__ att, int2* __restrict__ edgesT) {
  const int wave = threadIdx.x >> 6;
  const int lane = threadIdx.x & 63;
  const int row = blockIdx.x * 4 + wave;
  const int d = deg[row];
  const int* cols = nbr + (size_t)row * MAXD;
  const float w1r = Wh1[row];
  const float w2r = Wh2[row];
  const float mr = mrow[row];
  const float invZr = 1.0f / Zrow[row];
  for (int t = lane; t < d; t += 64) {
    const int j = cols[t];
    float e = w1r + Wh2[j];
    e = e > 0.0f ? e : LRALPHA * e;
    att[(size_t)row * MAXD + t] = expf(e - mr) * invZr;
    float e2 = Wh1[j] + w2r;
    e2 = e2 > 0.0f ? e2 : LRALPHA * e2;
    const float v = expf(e2 - mrow[j]) / Zrow[j];
    edgesT[(size_t)row * MAXD + t] = make_int2(j, __float_as_int(v));
  }
}

// ---------------------------------------------------------------------------
// Kernel E: per row i, 256 threads (4 waves). comb row lives in LDS.
// Column-partitioned scatter: wave w owns columns [w*2048,(w+1)*2048) ->
// no write collisions, no barriers in the k loop, deterministic order.
// Then radix-select the s2-th largest and emit the binary row.
// ---------------------------------------------------------------------------
__global__ void __launch_bounds__(256) k_twostep(
    const int* __restrict__ nbr, const int* __restrict__ deg,
    const int* __restrict__ s2v, const float* __restrict__ att,
    const int2* __restrict__ edgesT, float* __restrict__ out1) {
  __shared__ float comb[NN];
  __shared__ float wvals[MAXD];
  __shared__ int kcols[MAXD];
  __shared__ unsigned int hist[256];
  __shared__ unsigned int shPrefix;
  __shared__ int shRemaining;
  const int tid = threadIdx.x;
  const int wave = tid >> 6;
  const int lane = tid & 63;
  const int row = blockIdx.x;
  const float4 z4 = make_float4(0.0f, 0.0f, 0.0f, 0.0f);
  for (int j = tid * 4; j < NN; j += 1024)
    *reinterpret_cast<float4*>(&comb[j]) = z4;
  const int d = deg[row];
  const int* cols = nbr + (size_t)row * MAXD;
  const float* arow = att + (size_t)row * MAXD;
  for (int t = tid; t < d; t += 256) {
    kcols[t] = cols[t];
    wvals[t] = arow[t];
  }
  __syncthreads();
  // scatter phase: each wave filters to its own column range
  const int clo = wave << 11;
  const int chi = clo + 2048;
  for (int kidx = 0; kidx < d; ++kidx) {
    const int k = kcols[kidx];
    const float w = wvals[kidx];
    const int dk = deg[k];
    const int2* ek = edgesT + (size_t)k * MAXD;
    for (int t = lane; t < dk; t += 64) {
      const int2 e = ek[t];
      if (e.x >= clo && e.x < chi) comb[e.x] += w * __int_as_float(e.y);
    }
  }
  for (int t = lane; t < d; t += 64) {
    const int c = kcols[t];
    if (c >= clo && c < chi) comb[c] += wvals[t];
  }
  __syncthreads();
  if (tid == 0) comb[row] = 0.0f;
  __syncthreads();
  const int kk = s2v[row];
  const size_t obase = (size_t)row * NN;
  if (kk <= 0) {
    for (int j = tid * 4; j < NN; j += 1024)
      *reinterpret_cast<float4*>(&out1[obase + j]) = z4;
    return;
  }
  // radix select: kk-th largest of comb (all values >= 0 -> uint order).
  unsigned int prefix = 0u;
  int remaining = kk;
  for (int pass = 0; pass < 4; ++pass) {
    const int shift = 24 - 8 * pass;
    const unsigned int pmask = (pass == 0) ? 0u : (0xFFFFFFFFu << (shift + 8));
    hist[tid] = 0u;
    __syncthreads();
    for (int j = tid; j < NN; j += 256) {
      const unsigned int u = __float_as_uint(comb[j]);
      if ((u & pmask) == prefix) atomicAdd(&hist[(u >> shift) & 255u], 1u);
    }
    __syncthreads();
    if (tid < 64) {
      const int bHi = 255 - 4 * lane;  // lane 0 owns highest bins
      const unsigned int c0 = hist[bHi];
      const unsigned int c1 = hist[bHi - 1];
      const unsigned int c2 = hist[bHi - 2];
      const unsigned int c3 = hist[bHi - 3];
      const unsigned int gs = c0 + c1 + c2 + c3;
      unsigned int run = gs;
      for (int o = 1; o < 64; o <<= 1) {
        const unsigned int tt = __shfl_up(run, o);
        if (lane >= o) run += tt;
      }
      const unsigned int pre = run - gs;  // count in strictly higher bins
      const unsigned int rem = (unsigned int)remaining;
      if (pre < rem && pre + gs >= rem) {  // exactly one lane hits
        unsigned int above;
        int digit;
        if (pre + c0 >= rem) { digit = bHi; above = pre; }
        else if (pre + c0 + c1 >= rem) { digit = bHi - 1; above = pre + c0; }
        else if (pre + c0 + c1 + c2 >= rem) { digit = bHi - 2; above = pre + c0 + c1; }
        else { digit = bHi - 3; above = pre + c0 + c1 + c2; }
        shPrefix = prefix | ((unsigned int)digit << shift);
        shRemaining = remaining - (int)above;
      }
    }
    __syncthreads();
    prefix = shPrefix;
    remaining = shRemaining;
    __syncthreads();
  }
  const float thr = __uint_as_float(prefix);  // exact kk-th largest value
  for (int j = tid * 4; j < NN; j += 1024) {
    const float4 cv = *reinterpret_cast<const float4*>(&comb[j]);
    float4 ov;
    ov.x = (cv.x >= thr && cv.x > 0.0f) ? 1.0f : 0.0f;
    ov.y = (cv.y >= thr && cv.y > 0.0f) ? 1.0f : 0.0f;
    ov.z = (cv.z >= thr && cv.z > 0.0f) ? 1.0f : 0.0f;
    ov.w = (cv.w >= thr && cv.w > 0.0f) ? 1.0f : 0.0f;
    *reinterpret_cast<float4*>(&out1[obase + j]) = ov;
  }
}

// ---------------------------------------------------------------------------
// Kernel F: h_prime = attention @ Wh (sparse x dense), then ELU.
// One block per row; cols/vals staged in LDS; 4-way partial sums for MLP.
// ---------------------------------------------------------------------------
__global__ void __launch_bounds__(256) k_hprime(
    const int* __restrict__ nbr, const int* __restrict__ deg,
    const float* __restrict__ att, const float* __restrict__ Wh,
    float* __restrict__ out0) {
  __shared__ int scol[MAXD];
  __shared__ float sval[MAXD];
  const int row = blockIdx.x;
  const int c = threadIdx.x;
  const int d = deg[row];
  const int* cols = nbr + (size_t)row * MAXD;
  const float* arow = att + (size_t)row * MAXD;
  for (int t = threadIdx.x; t < d; t += 256) {
    scol[t] = cols[t];
    sval[t] = arow[t];
  }
  __syncthreads();
  float a0 = 0.0f, a1 = 0.0f, a2 = 0.0f, a3 = 0.0f;
  int t = 0;
  for (; t + 4 <= d; t += 4) {
    a0 += sval[t + 0] * Wh[(size_t)scol[t + 0] * KFOUT + c];
    a1 += sval[t + 1] * Wh[(size_t)scol[t + 1] * KFOUT + c];
    a2 += sval[t + 2] * Wh[(size_t)scol[t + 2] * KFOUT + c];
    a3 += sval[t + 3] * Wh[(size_t)scol[t + 3] * KFOUT + c];
  }
  for (; t < d; ++t) a0 += sval[t] * Wh[(size_t)scol[t] * KFOUT + c];
  const float acc = (a0 + a1) + (a2 + a3);
  out0[(size_t)row * KFOUT + c] = acc > 0.0f ? acc : expm1f(acc);
}

extern "C" void kernel_launch(void* const* d_in, const int* in_sizes, int n_in,
                              void* d_out, int out_size, void* d_ws, size_t ws_size,
                              hipStream_t stream) {
  const float* h = (const float*)d_in[0];
  const float* adj = (const float*)d_in[1];
  const float* W = (const float*)d_in[2];
  const float* a = (const float*)d_in[3];

  float* out0 = (float*)d_out;                  // [8192, 256] elu(h_prime)
  float* out1 = out0 + (size_t)NN * KFOUT;      // [8192, 8192] adj_resize

  // workspace layout (~33.8 MB)
  float* Wh = (float*)d_ws;                        // 8192*256
  float* Wh1 = Wh + (size_t)NN * KFOUT;            // 8192
  float* Wh2 = Wh1 + NN;                           // 8192
  float* mrow = Wh2 + NN;                          // 8192
  float* Zrow = mrow + NN;                         // 8192
  float* att = Zrow + NN;                          // 8192*MAXD
  float* edgesF = att + (size_t)NN * MAXD;         // 8192*MAXD int2
  int2* edgesT = (int2*)edgesF;
  int* nbr = (int*)(edgesF + (size_t)NN * MAXD * 2);  // 8192*MAXD
  int* deg = nbr + (size_t)NN * MAXD;              // 8192
  int* s2v = deg + NN;                             // 8192

  k_build_csr<<<NN / 4, 256, 0, stream>>>(adj, nbr, deg, s2v);
  dim3 ggrid(KFOUT / 64, NN / 64);
  k_gemm<<<ggrid, 256, 0, stream>>>(h, W, Wh);
  k_rowdots<<<NN, 256, 0, stream>>>(Wh, a, Wh1, Wh2);
  k_stats<<<NN / 4, 256, 0, stream>>>(nbr, deg, Wh1, Wh2, mrow, Zrow);
  k_att<<<NN / 4, 256, 0, stream>>>(nbr, deg, Wh1, Wh2, mrow, Zrow, att, edgesT);
  k_twostep<<<NN, 256, 0, stream>>>(nbr, deg, s2v, att, edgesT, out1);
  k_hprime<<<NN, 256, 0, stream>>>(nbr, deg, att, Wh, out0);
}

// Round 3
// 597.381 us; speedup vs baseline: 1.6964x; 1.3329x over previous
//
#include <hip/hip_runtime.h>
#include <cstdint>
#include <cstddef>

#define NN 8192
#define KFIN 1024
#define KFOUT 256
#define MAXD 192
#define LRALPHA 0.2f

typedef float f32x4 __attribute__((ext_vector_type(4)));

// ---------------------------------------------------------------------------
// Kernel A: dense adj -> CSR neighbor lists (stable order via 4x ballot on
// float4 nontemporal loads), degree, and s2 = off-diagonal degree.
// ---------------------------------------------------------------------------
__global__ void __launch_bounds__(256) k_build_csr(
    const float* __restrict__ adj, int* __restrict__ nbr,
    int* __restrict__ deg, int* __restrict__ s2v) {
  const int wave = threadIdx.x >> 6;
  const int lane = threadIdx.x & 63;
  const int row = blockIdx.x * 4 + wave;
  const float* arow = adj + (size_t)row * NN;
  int* outp = nbr + (size_t)row * MAXD;
  int count = 0;
  int dflag = 0;
  const unsigned long long below = (1ull << lane) - 1ull;
  for (int c0 = 0; c0 < NN; c0 += 256) {
    const int c = c0 + lane * 4;
    const f32x4 v = __builtin_nontemporal_load(
        reinterpret_cast<const f32x4*>(arow + c));
    const unsigned long long m0 = __ballot(v[0] > 0.0f);
    const unsigned long long m1 = __ballot(v[1] > 0.0f);
    const unsigned long long m2 = __ballot(v[2] > 0.0f);
    const unsigned long long m3 = __ballot(v[3] > 0.0f);
    int pos = count + (int)(__popcll(m0 & below) + __popcll(m1 & below) +
                            __popcll(m2 & below) + __popcll(m3 & below));
    if (v[0] > 0.0f) { if (pos < MAXD) outp[pos] = c + 0; ++pos; if (c + 0 == row) dflag = 1; }
    if (v[1] > 0.0f) { if (pos < MAXD) outp[pos] = c + 1; ++pos; if (c + 1 == row) dflag = 1; }
    if (v[2] > 0.0f) { if (pos < MAXD) outp[pos] = c + 2; ++pos; if (c + 2 == row) dflag = 1; }
    if (v[3] > 0.0f) { if (pos < MAXD) outp[pos] = c + 3; ++pos; if (c + 3 == row) dflag = 1; }
    count += (int)(__popcll(m0) + __popcll(m1) + __popcll(m2) + __popcll(m3));
  }
  const int anyd = __any(dflag) ? 1 : 0;
  if (lane == 0) {
    deg[row] = count < MAXD ? count : MAXD;
    s2v[row] = count - anyd;
  }
}

// ---------------------------------------------------------------------------
// Kernel B: Wh = h @ W, f32 tiled GEMM (64x64 tile, 4x4 per thread, BK=16).
// ---------------------------------------------------------------------------
__global__ void __launch_bounds__(256) k_gemm(
    const float* __restrict__ A, const float* __restrict__ B,
    float* __restrict__ C) {
  __shared__ float As[16][65];
  __shared__ float Bs[16][65];
  const int tid = threadIdx.x;
  const int brow = blockIdx.y * 64;
  const int bcol = blockIdx.x * 64;
  const int tx = tid & 15;
  const int ty = tid >> 4;
  float acc[4][4];
#pragma unroll
  for (int i = 0; i < 4; ++i)
#pragma unroll
    for (int j = 0; j < 4; ++j) acc[i][j] = 0.0f;
  const int ar = tid >> 2;
  const int ac = (tid & 3) << 2;
  const int br = tid >> 4;
  const int bc = (tid & 15) << 2;
  for (int k0 = 0; k0 < KFIN; k0 += 16) {
    const float4 av =
        *reinterpret_cast<const float4*>(A + (size_t)(brow + ar) * KFIN + k0 + ac);
    const float4 bv =
        *reinterpret_cast<const float4*>(B + (size_t)(k0 + br) * KFOUT + bcol + bc);
    As[ac + 0][ar] = av.x;
    As[ac + 1][ar] = av.y;
    As[ac + 2][ar] = av.z;
    As[ac + 3][ar] = av.w;
    Bs[br][bc + 0] = bv.x;
    Bs[br][bc + 1] = bv.y;
    Bs[br][bc + 2] = bv.z;
    Bs[br][bc + 3] = bv.w;
    __syncthreads();
#pragma unroll
    for (int kk = 0; kk < 16; ++kk) {
      const float a0 = As[kk][ty * 4 + 0];
      const float a1 = As[kk][ty * 4 + 1];
      const float a2 = As[kk][ty * 4 + 2];
      const float a3 = As[kk][ty * 4 + 3];
      const float b0 = Bs[kk][tx * 4 + 0];
      const float b1 = Bs[kk][tx * 4 + 1];
      const float b2 = Bs[kk][tx * 4 + 2];
      const float b3 = Bs[kk][tx * 4 + 3];
      acc[0][0] += a0 * b0; acc[0][1] += a0 * b1; acc[0][2] += a0 * b2; acc[0][3] += a0 * b3;
      acc[1][0] += a1 * b0; acc[1][1] += a1 * b1; acc[1][2] += a1 * b2; acc[1][3] += a1 * b3;
      acc[2][0] += a2 * b0; acc[2][1] += a2 * b1; acc[2][2] += a2 * b2; acc[2][3] += a2 * b3;
      acc[3][0] += a3 * b0; acc[3][1] += a3 * b1; acc[3][2] += a3 * b2; acc[3][3] += a3 * b3;
    }
    __syncthreads();
  }
#pragma unroll
  for (int i = 0; i < 4; ++i) {
#pragma unroll
    for (int j = 0; j < 4; ++j) {
      C[(size_t)(brow + ty * 4 + i) * KFOUT + bcol + tx * 4 + j] = acc[i][j];
    }
  }
}

// ---------------------------------------------------------------------------
// Kernel C: Wh1 = Wh @ a[:256], Wh2 = Wh @ a[256:], one block per row.
// ---------------------------------------------------------------------------
__global__ void __launch_bounds__(256) k_rowdots(
    const float* __restrict__ Wh, const float* __restrict__ a,
    float* __restrict__ Wh1, float* __restrict__ Wh2) {
  __shared__ float sA[256];
  __shared__ float sB[256];
  const int row = blockIdx.x;
  const int t = threadIdx.x;
  const float w = Wh[(size_t)row * KFOUT + t];
  sA[t] = w * a[t];
  sB[t] = w * a[KFOUT + t];
  __syncthreads();
  for (int s = 128; s > 0; s >>= 1) {
    if (t < s) {
      sA[t] += sA[t + s];
      sB[t] += sB[t + s];
    }
    __syncthreads();
  }
  if (t == 0) {
    Wh1[row] = sA[0];
    Wh2[row] = sB[0];
  }
}

// ---------------------------------------------------------------------------
// Kernel D1: per-row softmax stats (max m, denom Z) over neighbor list.
// ---------------------------------------------------------------------------
__global__ void __launch_bounds__(256) k_stats(
    const int* __restrict__ nbr, const int* __restrict__ deg,
    const float* __restrict__ Wh1, const float* __restrict__ Wh2,
    float* __restrict__ mrow, float* __restrict__ Zrow) {
  const int wave = threadIdx.x >> 6;
  const int lane = threadIdx.x & 63;
  const int row = blockIdx.x * 4 + wave;
  const int d = deg[row];
  const int* cols = nbr + (size_t)row * MAXD;
  const float w1 = Wh1[row];
  float mx = -1e30f;
  for (int t = lane; t < d; t += 64) {
    float e = w1 + Wh2[cols[t]];
    e = e > 0.0f ? e : LRALPHA * e;
    mx = fmaxf(mx, e);
  }
  for (int o = 32; o > 0; o >>= 1) mx = fmaxf(mx, __shfl_xor(mx, o));
  float sum = 0.0f;
  for (int t = lane; t < d; t += 64) {
    float e = w1 + Wh2[cols[t]];
    e = e > 0.0f ? e : LRALPHA * e;
    sum += expf(e - mx);
  }
  for (int o = 32; o > 0; o >>= 1) sum += __shfl_xor(sum, o);
  if (lane == 0) {
    mrow[row] = mx;
    Zrow[row] = (d > 0) ? sum : 1.0f;
  }
}

// ---------------------------------------------------------------------------
// Kernel D2: attention CSR values + packed transpose-edge values.
// ---------------------------------------------------------------------------
__global__ void __launch_bounds__(256) k_att(
    const int* __restrict__ nbr, const int* __restrict__ deg,
    const float* __restrict__ Wh1, const float* __restrict__ Wh2,
    const float* __restrict__ mrow, const float* __restrict__ Zrow,
    float* __restrict__ att, int2* __restrict__ edgesT) {
  const int wave = threadIdx.x >> 6;
  const int lane = threadIdx.x & 63;
  const int row = blockIdx.x * 4 + wave;
  const int d = deg[row];
  const int* cols = nbr + (size_t)row * MAXD;
  const float w1r = Wh1[row];
  const float w2r = Wh2[row];
  const float mr = mrow[row];
  const float invZr = 1.0f / Zrow[row];
  for (int t = lane; t < d; t += 64) {
    const int j = cols[t];
    float e = w1r + Wh2[j];
    e = e > 0.0f ? e : LRALPHA * e;
    att[(size_t)row * MAXD + t] = expf(e - mr) * invZr;
    float e2 = Wh1[j] + w2r;
    e2 = e2 > 0.0f ? e2 : LRALPHA * e2;
    const float v = expf(e2 - mrow[j]) / Zrow[j];
    edgesT[(size_t)row * MAXD + t] = make_int2(j, __float_as_int(v));
  }
}

// ---------------------------------------------------------------------------
// Kernel E: per row i, 256 threads (4 waves), comb row in LDS.
// Column-partitioned scatter (wave w owns cols [w*2048,(w+1)*2048)):
// no collisions, no barriers in k loop, deterministic order.
// Depth-2 register prefetch of edge data removes the serial latency chain.
// Then radix-select the s2-th largest and emit the binary row (nt stores).
// ---------------------------------------------------------------------------
__global__ void __launch_bounds__(256) k_twostep(
    const int* __restrict__ nbr, const int* __restrict__ deg,
    const int* __restrict__ s2v, const float* __restrict__ att,
    const int2* __restrict__ edgesT, float* __restrict__ out1) {
  __shared__ float comb[NN];
  __shared__ float wvals[MAXD];
  __shared__ int kcols[MAXD];
  __shared__ int sdeg[MAXD];
  __shared__ unsigned int hist[256];
  __shared__ unsigned int shPrefix;
  __shared__ int shRemaining;
  const int tid = threadIdx.x;
  const int wave = tid >> 6;
  const int lane = tid & 63;
  const int row = blockIdx.x;
  const f32x4 z4 = {0.0f, 0.0f, 0.0f, 0.0f};
  for (int j = tid * 4; j < NN; j += 1024)
    *reinterpret_cast<f32x4*>(&comb[j]) = z4;
  const int d = deg[row];
  const int* cols = nbr + (size_t)row * MAXD;
  const float* arow = att + (size_t)row * MAXD;
  for (int t = tid; t < d; t += 256) {
    const int c = cols[t];
    kcols[t] = c;
    wvals[t] = arow[t];
    sdeg[t] = deg[c];   // gathered once; removes deg from the k-loop chain
  }
  __syncthreads();
  // scatter phase: each wave filters to its own column range
  const int clo = wave << 11;
  const int chi = clo + 2048;
  {
    // depth-2 software pipeline: slots A (kidx) and B (kidx+1)
    int2 a0, a1, b0, b1;
    int adk = 0, bdk = 0;
    float aw = 0.0f, bw = 0.0f;
    const int2 *aek = edgesT, *bek = edgesT;
#define ISSUE_SLOT(e0_, e1_, dk_, w_, ek_, KI)                        \
    {                                                                  \
      const int k_ = kcols[KI];                                        \
      dk_ = sdeg[KI];                                                  \
      w_ = wvals[KI];                                                  \
      ek_ = edgesT + (size_t)k_ * MAXD;                                \
      e0_ = ek_[lane];        /* unconditional: always valid memory */ \
      e1_ = ek_[lane + 64];                                            \
    }
    if (d > 0) ISSUE_SLOT(a0, a1, adk, aw, aek, 0);
    if (d > 1) ISSUE_SLOT(b0, b1, bdk, bw, bek, 1);
    for (int kidx = 0; kidx < d; ++kidx) {
      const int2 e0 = a0, e1 = a1;
      const int cdk = adk;
      const float cw = aw;
      const int2* cek = aek;
      a0 = b0; a1 = b1; adk = bdk; aw = bw; aek = bek;
      if (kidx + 2 < d) ISSUE_SLOT(b0, b1, bdk, bw, bek, kidx + 2);
      if (lane < cdk && e0.x >= clo && e0.x < chi)
        comb[e0.x] += cw * __int_as_float(e0.y);
      if (lane + 64 < cdk && e1.x >= clo && e1.x < chi)
        comb[e1.x] += cw * __int_as_float(e1.y);
      for (int t = lane + 128; t < cdk; t += 64) {  // rare: dk > 128
        const int2 e = cek[t];
        if (e.x >= clo && e.x < chi) comb[e.x] += cw * __int_as_float(e.y);
      }
    }
#undef ISSUE_SLOT
  }
  for (int t = lane; t < d; t += 64) {
    const int c = kcols[t];
    if (c >= clo && c < chi) comb[c] += wvals[t];
  }
  __syncthreads();
  if (tid == 0) comb[row] = 0.0f;
  __syncthreads();
  const int kk = s2v[row];
  const size_t obase = (size_t)row * NN;
  if (kk <= 0) {
    for (int j = tid * 4; j < NN; j += 1024)
      __builtin_nontemporal_store(z4, reinterpret_cast<f32x4*>(&out1[obase + j]));
    return;
  }
  // radix select: kk-th largest of comb (all values >= 0 -> uint order).
  unsigned int prefix = 0u;
  int remaining = kk;
  for (int pass = 0; pass < 4; ++pass) {
    const int shift = 24 - 8 * pass;
    const unsigned int pmask = (pass == 0) ? 0u : (0xFFFFFFFFu << (shift + 8));
    hist[tid] = 0u;
    __syncthreads();
    for (int j = tid; j < NN; j += 256) {
      const unsigned int u = __float_as_uint(comb[j]);
      if ((u & pmask) == prefix) atomicAdd(&hist[(u >> shift) & 255u], 1u);
    }
    __syncthreads();
    if (tid < 64) {
      const int bHi = 255 - 4 * lane;  // lane 0 owns highest bins
      const unsigned int c0 = hist[bHi];
      const unsigned int c1 = hist[bHi - 1];
      const unsigned int c2 = hist[bHi - 2];
      const unsigned int c3 = hist[bHi - 3];
      const unsigned int gs = c0 + c1 + c2 + c3;
      unsigned int run = gs;
      for (int o = 1; o < 64; o <<= 1) {
        const unsigned int tt = __shfl_up(run, o);
        if (lane >= o) run += tt;
      }
      const unsigned int pre = run - gs;  // count in strictly higher bins
      const unsigned int rem = (unsigned int)remaining;
      if (pre < rem && pre + gs >= rem) {  // exactly one lane hits
        unsigned int above;
        int digit;
        if (pre + c0 >= rem) { digit = bHi; above = pre; }
        else if (pre + c0 + c1 >= rem) { digit = bHi - 1; above = pre + c0; }
        else if (pre + c0 + c1 + c2 >= rem) { digit = bHi - 2; above = pre + c0 + c1; }
        else { digit = bHi - 3; above = pre + c0 + c1 + c2; }
        shPrefix = prefix | ((unsigned int)digit << shift);
        shRemaining = remaining - (int)above;
      }
    }
    __syncthreads();
    prefix = shPrefix;
    remaining = shRemaining;
    __syncthreads();
  }
  const float thr = __uint_as_float(prefix);  // exact kk-th largest value
  for (int j = tid * 4; j < NN; j += 1024) {
    const f32x4 cv = *reinterpret_cast<const f32x4*>(&comb[j]);
    f32x4 ov;
    ov[0] = (cv[0] >= thr && cv[0] > 0.0f) ? 1.0f : 0.0f;
    ov[1] = (cv[1] >= thr && cv[1] > 0.0f) ? 1.0f : 0.0f;
    ov[2] = (cv[2] >= thr && cv[2] > 0.0f) ? 1.0f : 0.0f;
    ov[3] = (cv[3] >= thr && cv[3] > 0.0f) ? 1.0f : 0.0f;
    __builtin_nontemporal_store(ov, reinterpret_cast<f32x4*>(&out1[obase + j]));
  }
}

// ---------------------------------------------------------------------------
// Kernel F: h_prime = attention @ Wh (sparse x dense), then ELU.
// ---------------------------------------------------------------------------
__global__ void __launch_bounds__(256) k_hprime(
    const int* __restrict__ nbr, const int* __restrict__ deg,
    const float* __restrict__ att, const float* __restrict__ Wh,
    float* __restrict__ out0) {
  __shared__ int scol[MAXD];
  __shared__ float sval[MAXD];
  const int row = blockIdx.x;
  const int c = threadIdx.x;
  const int d = deg[row];
  const int* cols = nbr + (size_t)row * MAXD;
  const float* arow = att + (size_t)row * MAXD;
  for (int t = threadIdx.x; t < d; t += 256) {
    scol[t] = cols[t];
    sval[t] = arow[t];
  }
  __syncthreads();
  float a0 = 0.0f, a1 = 0.0f, a2 = 0.0f, a3 = 0.0f;
  int t = 0;
  for (; t + 4 <= d; t += 4) {
    a0 += sval[t + 0] * Wh[(size_t)scol[t + 0] * KFOUT + c];
    a1 += sval[t + 1] * Wh[(size_t)scol[t + 1] * KFOUT + c];
    a2 += sval[t + 2] * Wh[(size_t)scol[t + 2] * KFOUT + c];
    a3 += sval[t + 3] * Wh[(size_t)scol[t + 3] * KFOUT + c];
  }
  for (; t < d; ++t) a0 += sval[t] * Wh[(size_t)scol[t] * KFOUT + c];
  const float acc = (a0 + a1) + (a2 + a3);
  out0[(size_t)row * KFOUT + c] = acc > 0.0f ? acc : expm1f(acc);
}

extern "C" void kernel_launch(void* const* d_in, const int* in_sizes, int n_in,
                              void* d_out, int out_size, void* d_ws, size_t ws_size,
                              hipStream_t stream) {
  const float* h = (const float*)d_in[0];
  const float* adj = (const float*)d_in[1];
  const float* W = (const float*)d_in[2];
  const float* a = (const float*)d_in[3];

  float* out0 = (float*)d_out;                  // [8192, 256] elu(h_prime)
  float* out1 = out0 + (size_t)NN * KFOUT;      // [8192, 8192] adj_resize

  // workspace layout (~33.8 MB)
  float* Wh = (float*)d_ws;                        // 8192*256
  float* Wh1 = Wh + (size_t)NN * KFOUT;            // 8192
  float* Wh2 = Wh1 + NN;                           // 8192
  float* mrow = Wh2 + NN;                          // 8192
  float* Zrow = mrow + NN;                         // 8192
  float* att = Zrow + NN;                          // 8192*MAXD
  float* edgesF = att + (size_t)NN * MAXD;         // 8192*MAXD int2
  int2* edgesT = (int2*)edgesF;
  int* nbr = (int*)(edgesF + (size_t)NN * MAXD * 2);  // 8192*MAXD
  int* deg = nbr + (size_t)NN * MAXD;              // 8192
  int* s2v = deg + NN;                             // 8192

  k_build_csr<<<NN / 4, 256, 0, stream>>>(adj, nbr, deg, s2v);
  dim3 ggrid(KFOUT / 64, NN / 64);
  k_gemm<<<ggrid, 256, 0, stream>>>(h, W, Wh);
  k_rowdots<<<NN, 256, 0, stream>>>(Wh, a, Wh1, Wh2);
  k_stats<<<NN / 4, 256, 0, stream>>>(nbr, deg, Wh1, Wh2, mrow, Zrow);
  k_att<<<NN / 4, 256, 0, stream>>>(nbr, deg, Wh1, Wh2, mrow, Zrow, att, edgesT);
  k_twostep<<<NN, 256, 0, stream>>>(nbr, deg, s2v, att, edgesT, out1);
  k_hprime<<<NN, 256, 0, stream>>>(nbr, deg, att, Wh, out0);
}

// Round 4
// 517.140 us; speedup vs baseline: 1.9597x; 1.1552x over previous
//
#include <hip/hip_runtime.h>
#include <cstdint>
#include <cstddef>

#define NN 8192
#define KFIN 1024
#define KFOUT 256
#define MAXD 192
#define LRALPHA 0.2f

typedef float f32x4 __attribute__((ext_vector_type(4)));

// ---------------------------------------------------------------------------
// Kernel A: dense adj -> CSR neighbor lists (stable ascending-column order via
// 4x ballot on float4 nontemporal loads), degree, s2 = off-diagonal degree.
// ---------------------------------------------------------------------------
__global__ void __launch_bounds__(256) k_build_csr(
    const float* __restrict__ adj, int* __restrict__ nbr,
    int* __restrict__ deg, int* __restrict__ s2v) {
  const int wave = threadIdx.x >> 6;
  const int lane = threadIdx.x & 63;
  const int row = blockIdx.x * 4 + wave;
  const float* arow = adj + (size_t)row * NN;
  int* outp = nbr + (size_t)row * MAXD;
  int count = 0;
  int dflag = 0;
  const unsigned long long below = (1ull << lane) - 1ull;
  for (int c0 = 0; c0 < NN; c0 += 256) {
    const int c = c0 + lane * 4;
    const f32x4 v = __builtin_nontemporal_load(
        reinterpret_cast<const f32x4*>(arow + c));
    const unsigned long long m0 = __ballot(v[0] > 0.0f);
    const unsigned long long m1 = __ballot(v[1] > 0.0f);
    const unsigned long long m2 = __ballot(v[2] > 0.0f);
    const unsigned long long m3 = __ballot(v[3] > 0.0f);
    int pos = count + (int)(__popcll(m0 & below) + __popcll(m1 & below) +
                            __popcll(m2 & below) + __popcll(m3 & below));
    if (v[0] > 0.0f) { if (pos < MAXD) outp[pos] = c + 0; ++pos; if (c + 0 == row) dflag = 1; }
    if (v[1] > 0.0f) { if (pos < MAXD) outp[pos] = c + 1; ++pos; if (c + 1 == row) dflag = 1; }
    if (v[2] > 0.0f) { if (pos < MAXD) outp[pos] = c + 2; ++pos; if (c + 2 == row) dflag = 1; }
    if (v[3] > 0.0f) { if (pos < MAXD) outp[pos] = c + 3; ++pos; if (c + 3 == row) dflag = 1; }
    count += (int)(__popcll(m0) + __popcll(m1) + __popcll(m2) + __popcll(m3));
  }
  const int anyd = __any(dflag) ? 1 : 0;
  if (lane == 0) {
    deg[row] = count < MAXD ? count : MAXD;
    s2v[row] = count - anyd;
  }
}

// ---------------------------------------------------------------------------
// Kernel B: Wh = h @ W, f32 tiled GEMM (64x64 tile, 4x4 per thread, BK=16).
// ---------------------------------------------------------------------------
__global__ void __launch_bounds__(256) k_gemm(
    const float* __restrict__ A, const float* __restrict__ B,
    float* __restrict__ C) {
  __shared__ float As[16][65];
  __shared__ float Bs[16][65];
  const int tid = threadIdx.x;
  const int brow = blockIdx.y * 64;
  const int bcol = blockIdx.x * 64;
  const int tx = tid & 15;
  const int ty = tid >> 4;
  float acc[4][4];
#pragma unroll
  for (int i = 0; i < 4; ++i)
#pragma unroll
    for (int j = 0; j < 4; ++j) acc[i][j] = 0.0f;
  const int ar = tid >> 2;
  const int ac = (tid & 3) << 2;
  const int br = tid >> 4;
  const int bc = (tid & 15) << 2;
  for (int k0 = 0; k0 < KFIN; k0 += 16) {
    const float4 av =
        *reinterpret_cast<const float4*>(A + (size_t)(brow + ar) * KFIN + k0 + ac);
    const float4 bv =
        *reinterpret_cast<const float4*>(B + (size_t)(k0 + br) * KFOUT + bcol + bc);
    As[ac + 0][ar] = av.x;
    As[ac + 1][ar] = av.y;
    As[ac + 2][ar] = av.z;
    As[ac + 3][ar] = av.w;
    Bs[br][bc + 0] = bv.x;
    Bs[br][bc + 1] = bv.y;
    Bs[br][bc + 2] = bv.z;
    Bs[br][bc + 3] = bv.w;
    __syncthreads();
#pragma unroll
    for (int kk = 0; kk < 16; ++kk) {
      const float a0 = As[kk][ty * 4 + 0];
      const float a1 = As[kk][ty * 4 + 1];
      const float a2 = As[kk][ty * 4 + 2];
      const float a3 = As[kk][ty * 4 + 3];
      const float b0 = Bs[kk][tx * 4 + 0];
      const float b1 = Bs[kk][tx * 4 + 1];
      const float b2 = Bs[kk][tx * 4 + 2];
      const float b3 = Bs[kk][tx * 4 + 3];
      acc[0][0] += a0 * b0; acc[0][1] += a0 * b1; acc[0][2] += a0 * b2; acc[0][3] += a0 * b3;
      acc[1][0] += a1 * b0; acc[1][1] += a1 * b1; acc[1][2] += a1 * b2; acc[1][3] += a1 * b3;
      acc[2][0] += a2 * b0; acc[2][1] += a2 * b1; acc[2][2] += a2 * b2; acc[2][3] += a2 * b3;
      acc[3][0] += a3 * b0; acc[3][1] += a3 * b1; acc[3][2] += a3 * b2; acc[3][3] += a3 * b3;
    }
    __syncthreads();
  }
#pragma unroll
  for (int i = 0; i < 4; ++i) {
#pragma unroll
    for (int j = 0; j < 4; ++j) {
      C[(size_t)(brow + ty * 4 + i) * KFOUT + bcol + tx * 4 + j] = acc[i][j];
    }
  }
}

// ---------------------------------------------------------------------------
// Kernel C: Wh1 = Wh @ a[:256], Wh2 = Wh @ a[256:], one block per row.
// ---------------------------------------------------------------------------
__global__ void __launch_bounds__(256) k_rowdots(
    const float* __restrict__ Wh, const float* __restrict__ a,
    float* __restrict__ Wh1, float* __restrict__ Wh2) {
  __shared__ float sA[256];
  __shared__ float sB[256];
  const int row = blockIdx.x;
  const int t = threadIdx.x;
  const float w = Wh[(size_t)row * KFOUT + t];
  sA[t] = w * a[t];
  sB[t] = w * a[KFOUT + t];
  __syncthreads();
  for (int s = 128; s > 0; s >>= 1) {
    if (t < s) {
      sA[t] += sA[t + s];
      sB[t] += sB[t + s];
    }
    __syncthreads();
  }
  if (t == 0) {
    Wh1[row] = sA[0];
    Wh2[row] = sB[0];
  }
}

// ---------------------------------------------------------------------------
// Kernel D1: per-row softmax stats (max m, denom Z) over neighbor list.
// ---------------------------------------------------------------------------
__global__ void __launch_bounds__(256) k_stats(
    const int* __restrict__ nbr, const int* __restrict__ deg,
    const float* __restrict__ Wh1, const float* __restrict__ Wh2,
    float* __restrict__ mrow, float* __restrict__ Zrow) {
  const int wave = threadIdx.x >> 6;
  const int lane = threadIdx.x & 63;
  const int row = blockIdx.x * 4 + wave;
  const int d = deg[row];
  const int* cols = nbr + (size_t)row * MAXD;
  const float w1 = Wh1[row];
  float mx = -1e30f;
  for (int t = lane; t < d; t += 64) {
    float e = w1 + Wh2[cols[t]];
    e = e > 0.0f ? e : LRALPHA * e;
    mx = fmaxf(mx, e);
  }
  for (int o = 32; o > 0; o >>= 1) mx = fmaxf(mx, __shfl_xor(mx, o));
  float sum = 0.0f;
  for (int t = lane; t < d; t += 64) {
    float e = w1 + Wh2[cols[t]];
    e = e > 0.0f ? e : LRALPHA * e;
    sum += expf(e - mx);
  }
  for (int o = 32; o > 0; o >>= 1) sum += __shfl_xor(sum, o);
  if (lane == 0) {
    mrow[row] = mx;
    Zrow[row] = (d > 0) ? sum : 1.0f;
  }
}

// ---------------------------------------------------------------------------
// Kernel D2: attention CSR values + packed transpose-edge values + per-row
// column-quadrant split offsets (cols ascending -> quadrants contiguous).
// qb[row] = (count(col<2048), count(col<4096), count(col<6144), d)
// ---------------------------------------------------------------------------
__global__ void __launch_bounds__(256) k_att(
    const int* __restrict__ nbr, const int* __restrict__ deg,
    const float* __restrict__ Wh1, const float* __restrict__ Wh2,
    const float* __restrict__ mrow, const float* __restrict__ Zrow,
    float* __restrict__ att, int2* __restrict__ edgesT,
    short4* __restrict__ qb) {
  const int wave = threadIdx.x >> 6;
  const int lane = threadIdx.x & 63;
  const int row = blockIdx.x * 4 + wave;
  const int d = deg[row];
  const int* cols = nbr + (size_t)row * MAXD;
  const float w1r = Wh1[row];
  const float w2r = Wh2[row];
  const float mr = mrow[row];
  const float invZr = 1.0f / Zrow[row];
  int b1 = 0, b2 = 0, b3 = 0;
  for (int t0 = 0; t0 < d; t0 += 64) {
    const int t = t0 + lane;
    const bool act = t < d;
    const int j = act ? cols[t] : 0x7fffffff;
    b1 += (int)__popcll(__ballot(act && j < 2048));
    b2 += (int)__popcll(__ballot(act && j < 4096));
    b3 += (int)__popcll(__ballot(act && j < 6144));
    if (act) {
      float e = w1r + Wh2[j];
      e = e > 0.0f ? e : LRALPHA * e;
      att[(size_t)row * MAXD + t] = expf(e - mr) * invZr;
      float e2 = Wh1[j] + w2r;
      e2 = e2 > 0.0f ? e2 : LRALPHA * e2;
      const float v = expf(e2 - mrow[j]) / Zrow[j];
      edgesT[(size_t)row * MAXD + t] = make_int2(j, __float_as_int(v));
    }
  }
  if (lane == 0) {
    qb[row] = make_short4((short)b1, (short)b2, (short)b3, (short)d);
  }
}

// ---------------------------------------------------------------------------
// Kernel E: per row i, 256 threads (4 waves), comb row in LDS.
// Quadrant-partitioned scatter: wave w reads ONLY the contiguous segment of
// each neighbor k's edge list whose columns fall in [w*2048,(w+1)*2048).
// No filtering, each edge loaded once per block, no collisions, no barriers
// in the k loop, deterministic order (bitwise-identical to prior rounds).
// Depth-2 register prefetch. Then radix-select the s2-th largest (zeros
// skipped in histogram: threshold provably > 0) and emit binary row.
// ---------------------------------------------------------------------------
__global__ void __launch_bounds__(256) k_twostep(
    const int* __restrict__ nbr, const int* __restrict__ deg,
    const int* __restrict__ s2v, const float* __restrict__ att,
    const int2* __restrict__ edgesT, const short4* __restrict__ qbg,
    float* __restrict__ out1) {
  __shared__ float comb[NN];
  __shared__ float wvals[MAXD];
  __shared__ int kcols[MAXD];
  __shared__ short sqb[MAXD][4];
  __shared__ unsigned int hist[256];
  __shared__ unsigned int shPrefix;
  __shared__ int shRemaining;
  const int tid = threadIdx.x;
  const int wave = tid >> 6;
  const int lane = tid & 63;
  const int row = blockIdx.x;
  const f32x4 z4 = {0.0f, 0.0f, 0.0f, 0.0f};
  for (int j = tid * 4; j < NN; j += 1024)
    *reinterpret_cast<f32x4*>(&comb[j]) = z4;
  const int d = deg[row];
  const int* cols = nbr + (size_t)row * MAXD;
  const float* arow = att + (size_t)row * MAXD;
  for (int t = tid; t < d; t += 256) {
    const int c = cols[t];
    kcols[t] = c;
    wvals[t] = arow[t];
    *reinterpret_cast<short4*>(&sqb[t][0]) = qbg[c];
  }
  __syncthreads();
  const int clo = wave << 11;
  const int chi = clo + 2048;
  {
    // depth-2 software pipeline over neighbors; per-k this wave touches only
    // its quadrant segment [qs,qe) of k's edge list (predicated load).
    int2 a_e = make_int2(0, 0), b_e = make_int2(0, 0);
    int a_qs = 0, a_qe = 0, b_qs = 0, b_qe = 0;
    float a_w = 0.0f, b_w = 0.0f;
    const int2 *a_ek = edgesT, *b_ek = edgesT;
#define ISSUE_SLOT(E_, QS_, QE_, W_, EK_, KI)                          \
    {                                                                   \
      const int k_ = kcols[KI];                                         \
      W_ = wvals[KI];                                                   \
      QS_ = (wave == 0) ? 0 : (int)sqb[KI][wave - 1];                   \
      QE_ = (int)sqb[KI][wave];                                         \
      EK_ = edgesT + (size_t)k_ * MAXD;                                 \
      E_ = make_int2(0, 0);                                             \
      if (lane < QE_ - QS_) E_ = EK_[QS_ + lane];                       \
    }
    if (d > 0) ISSUE_SLOT(a_e, a_qs, a_qe, a_w, a_ek, 0);
    if (d > 1) ISSUE_SLOT(b_e, b_qs, b_qe, b_w, b_ek, 1);
    for (int kidx = 0; kidx < d; ++kidx) {
      const int2 e = a_e;
      const int qs = a_qs, qe = a_qe;
      const float w = a_w;
      const int2* ek = a_ek;
      a_e = b_e; a_qs = b_qs; a_qe = b_qe; a_w = b_w; a_ek = b_ek;
      if (kidx + 2 < d) ISSUE_SLOT(b_e, b_qs, b_qe, b_w, b_ek, kidx + 2);
      if (lane < qe - qs) comb[e.x] += w * __int_as_float(e.y);
      for (int t = qs + 64 + lane; t < qe; t += 64) {  // rare: segment > 64
        const int2 e2 = ek[t];
        comb[e2.x] += w * __int_as_float(e2.y);
      }
    }
#undef ISSUE_SLOT
  }
  for (int t = lane; t < d; t += 64) {
    const int c = kcols[t];
    if (c >= clo && c < chi) comb[c] += wvals[t];
  }
  __syncthreads();
  if (tid == 0) comb[row] = 0.0f;
  __syncthreads();
  const int kk = s2v[row];
  const size_t obase = (size_t)row * NN;
  if (kk <= 0) {
    for (int j = tid * 4; j < NN; j += 1024)
      __builtin_nontemporal_store(z4, reinterpret_cast<f32x4*>(&out1[obase + j]));
    return;
  }
  // radix select: kk-th largest of comb. All values >= 0 -> uint order.
  // Threshold is provably > 0 (every off-diag neighbor col has att > 0 and
  // kk <= #off-diag neighbors), so zero entries can be skipped entirely.
  unsigned int prefix = 0u;
  int remaining = kk;
  for (int pass = 0; pass < 4; ++pass) {
    const int shift = 24 - 8 * pass;
    const unsigned int pmask = (pass == 0) ? 0u : (0xFFFFFFFFu << (shift + 8));
    hist[tid] = 0u;
    __syncthreads();
    for (int j = tid; j < NN; j += 256) {
      const unsigned int u = __float_as_uint(comb[j]);
      if (u != 0u && (u & pmask) == prefix)
        atomicAdd(&hist[(u >> shift) & 255u], 1u);
    }
    __syncthreads();
    if (tid < 64) {
      const int bHi = 255 - 4 * lane;  // lane 0 owns highest bins
      const unsigned int c0 = hist[bHi];
      const unsigned int c1 = hist[bHi - 1];
      const unsigned int c2 = hist[bHi - 2];
      const unsigned int c3 = hist[bHi - 3];
      const unsigned int gs = c0 + c1 + c2 + c3;
      unsigned int run = gs;
      for (int o = 1; o < 64; o <<= 1) {
        const unsigned int tt = __shfl_up(run, o);
        if (lane >= o) run += tt;
      }
      const unsigned int pre = run - gs;  // count in strictly higher bins
      const unsigned int rem = (unsigned int)remaining;
      if (pre < rem && pre + gs >= rem) {  // exactly one lane hits
        unsigned int above;
        int digit;
        if (pre + c0 >= rem) { digit = bHi; above = pre; }
        else if (pre + c0 + c1 >= rem) { digit = bHi - 1; above = pre + c0; }
        else if (pre + c0 + c1 + c2 >= rem) { digit = bHi - 2; above = pre + c0 + c1; }
        else { digit = bHi - 3; above = pre + c0 + c1 + c2; }
        shPrefix = prefix | ((unsigned int)digit << shift);
        shRemaining = remaining - (int)above;
      }
    }
    __syncthreads();
    prefix = shPrefix;
    remaining = shRemaining;
    __syncthreads();
  }
  const float thr = __uint_as_float(prefix);  // exact kk-th largest value
  for (int j = tid * 4; j < NN; j += 1024) {
    const f32x4 cv = *reinterpret_cast<const f32x4*>(&comb[j]);
    f32x4 ov;
    ov[0] = (cv[0] >= thr && cv[0] > 0.0f) ? 1.0f : 0.0f;
    ov[1] = (cv[1] >= thr && cv[1] > 0.0f) ? 1.0f : 0.0f;
    ov[2] = (cv[2] >= thr && cv[2] > 0.0f) ? 1.0f : 0.0f;
    ov[3] = (cv[3] >= thr && cv[3] > 0.0f) ? 1.0f : 0.0f;
    __builtin_nontemporal_store(ov, reinterpret_cast<f32x4*>(&out1[obase + j]));
  }
}

// ---------------------------------------------------------------------------
// Kernel F: h_prime = attention @ Wh (sparse x dense), then ELU.
// ---------------------------------------------------------------------------
__global__ void __launch_bounds__(256) k_hprime(
    const int* __restrict__ nbr, const int* __restrict__ deg,
    const float* __restrict__ att, const float* __restrict__ Wh,
    float* __restrict__ out0) {
  __shared__ int scol[MAXD];
  __shared__ float sval[MAXD];
  const int row = blockIdx.x;
  const int c = threadIdx.x;
  const int d = deg[row];
  const int* cols = nbr + (size_t)row * MAXD;
  const float* arow = att + (size_t)row * MAXD;
  for (int t = threadIdx.x; t < d; t += 256) {
    scol[t] = cols[t];
    sval[t] = arow[t];
  }
  __syncthreads();
  float a0 = 0.0f, a1 = 0.0f, a2 = 0.0f, a3 = 0.0f;
  int t = 0;
  for (; t + 4 <= d; t += 4) {
    a0 += sval[t + 0] * Wh[(size_t)scol[t + 0] * KFOUT + c];
    a1 += sval[t + 1] * Wh[(size_t)scol[t + 1] * KFOUT + c];
    a2 += sval[t + 2] * Wh[(size_t)scol[t + 2] * KFOUT + c];
    a3 += sval[t + 3] * Wh[(size_t)scol[t + 3] * KFOUT + c];
  }
  for (; t < d; ++t) a0 += sval[t] * Wh[(size_t)scol[t] * KFOUT + c];
  const float acc = (a0 + a1) + (a2 + a3);
  out0[(size_t)row * KFOUT + c] = acc > 0.0f ? acc : expm1f(acc);
}

extern "C" void kernel_launch(void* const* d_in, const int* in_sizes, int n_in,
                              void* d_out, int out_size, void* d_ws, size_t ws_size,
                              hipStream_t stream) {
  const float* h = (const float*)d_in[0];
  const float* adj = (const float*)d_in[1];
  const float* W = (const float*)d_in[2];
  const float* a = (const float*)d_in[3];

  float* out0 = (float*)d_out;                  // [8192, 256] elu(h_prime)
  float* out1 = out0 + (size_t)NN * KFOUT;      // [8192, 8192] adj_resize

  // workspace layout (~33.8 MB)
  float* Wh = (float*)d_ws;                        // 8192*256
  float* Wh1 = Wh + (size_t)NN * KFOUT;            // 8192
  float* Wh2 = Wh1 + NN;                           // 8192
  float* mrow = Wh2 + NN;                          // 8192
  float* Zrow = mrow + NN;                         // 8192
  float* att = Zrow + NN;                          // 8192*MAXD
  float* edgesF = att + (size_t)NN * MAXD;         // 8192*MAXD int2
  int2* edgesT = (int2*)edgesF;
  int* nbr = (int*)(edgesF + (size_t)NN * MAXD * 2);  // 8192*MAXD
  int* deg = nbr + (size_t)NN * MAXD;              // 8192
  int* s2v = deg + NN;                             // 8192
  short4* qb = (short4*)(s2v + NN);                // 8192 (64 KB)

  k_build_csr<<<NN / 4, 256, 0, stream>>>(adj, nbr, deg, s2v);
  dim3 ggrid(KFOUT / 64, NN / 64);
  k_gemm<<<ggrid, 256, 0, stream>>>(h, W, Wh);
  k_rowdots<<<NN, 256, 0, stream>>>(Wh, a, Wh1, Wh2);
  k_stats<<<NN / 4, 256, 0, stream>>>(nbr, deg, Wh1, Wh2, mrow, Zrow);
  k_att<<<NN / 4, 256, 0, stream>>>(nbr, deg, Wh1, Wh2, mrow, Zrow, att, edgesT, qb);
  k_twostep<<<NN, 256, 0, stream>>>(nbr, deg, s2v, att, edgesT, qb, out1);
  k_hprime<<<NN, 256, 0, stream>>>(nbr, deg, att, Wh, out0);
}